// Round 5
// baseline (148.843 us; speedup 1.0000x reference)
//
#include <hip/hip_runtime.h>
#include <hip/hip_bf16.h>

#define K_DIM 4096
#define M_DIM 4096
#define T_DIM 2048
#define NB    1024
#define BT    128
#define LSTRIDE 64

typedef __attribute__((ext_vector_type(8))) short bf16x8;
typedef __attribute__((ext_vector_type(4))) float f32x4;

__device__ __forceinline__ unsigned short f2bf(float f) {
    unsigned int u = __builtin_bit_cast(unsigned int, f);
    unsigned int r = (u + 0x7FFFu + ((u >> 16) & 1u)) >> 16;
    return (unsigned short)r;
}

__device__ __forceinline__ void gld16(const void* g, void* l) {
    __builtin_amdgcn_global_load_lds(
        (const __attribute__((address_space(1))) unsigned int*)g,
        (__attribute__((address_space(3))) unsigned int*)l, 16, 0, 0);
}

// ---- fused prepass ----
// blocks [0, NPREP): x fp32 -> xb2 bf16 [64 c][2048 t][64 k] (transposed),
//                    values fp32 -> vb bf16 (linear)
// block NPREP: build per-r schedule: counts[64], lists[64][LSTRIDE] of (n | c<<16)
#define XCHUNKS (T_DIM * K_DIM / 8)   // 1,048,576
#define VCHUNKS (NB * 64 * 64 / 8)    //   524,288
#define NPREP   ((XCHUNKS + VCHUNKS) / 256)   // 6144

__global__ __launch_bounds__(256) void prep_kernel(
    const float* __restrict__ x, const float* __restrict__ values,
    unsigned short* __restrict__ xb2, unsigned short* __restrict__ vb,
    const int* __restrict__ brows, const int* __restrict__ bcols,
    int* __restrict__ counts, unsigned int* __restrict__ lists)
{
    __shared__ int scnt[64];
    const int blk = blockIdx.x;
    if (blk == NPREP) {
        const int tid = threadIdx.x;
        if (tid < 64) scnt[tid] = 0;
        __syncthreads();
        for (int n = tid; n < NB; n += 256) {
            const int r = brows[n];
            const int p = atomicAdd(&scnt[r], 1);
            if (p < LSTRIDE)
                lists[r * LSTRIDE + p] = (unsigned)n | ((unsigned)bcols[n] << 16);
        }
        __syncthreads();
        if (tid < 64) counts[tid] = scnt[tid] < LSTRIDE ? scnt[tid] : LSTRIDE;
        return;
    }
    const int id = blk * 256 + threadIdx.x;
    if (id < XCHUNKS) {
        const int t   = id >> 9;
        const int rem = id & 511;
        const int c   = rem >> 3;
        const int o   = rem & 7;
        const float4* p = (const float4*)(x + (size_t)t * K_DIM + c * 64 + o * 8);
        const float4 a = p[0], b = p[1];
        uint4 w;
        w.x = (unsigned)f2bf(a.x) | ((unsigned)f2bf(a.y) << 16);
        w.y = (unsigned)f2bf(a.z) | ((unsigned)f2bf(a.w) << 16);
        w.z = (unsigned)f2bf(b.x) | ((unsigned)f2bf(b.y) << 16);
        w.w = (unsigned)f2bf(b.z) | ((unsigned)f2bf(b.w) << 16);
        *(uint4*)(xb2 + ((size_t)c * T_DIM + t) * 64 + o * 8) = w;
    } else {
        const int i = id - XCHUNKS;
        const float4* p = (const float4*)(values + (size_t)i * 8);
        const float4 a = p[0], b = p[1];
        uint4 w;
        w.x = (unsigned)f2bf(a.x) | ((unsigned)f2bf(a.y) << 16);
        w.y = (unsigned)f2bf(a.z) | ((unsigned)f2bf(a.w) << 16);
        w.z = (unsigned)f2bf(b.x) | ((unsigned)f2bf(b.y) << 16);
        w.w = (unsigned)f2bf(b.z) | ((unsigned)f2bf(b.w) << 16);
        *(uint4*)(vb + (size_t)i * 8) = w;
    }
}

// ---- main: BT=128 tile, A in 3-buffer swizzled LDS (gld16, 2-deep),
// ----       B 2-deep in registers, counted vmcnt, raw barriers ----
__global__ __launch_bounds__(256, 3) void fsl_main(
    const unsigned short* __restrict__ xb2, const unsigned short* __restrict__ vb,
    const float* __restrict__ bias, const int* __restrict__ counts,
    const unsigned int* __restrict__ lists, float* __restrict__ out)
{
    __shared__ __align__(16) unsigned char sA[3][BT * 128];   // 48 KB

    const int b     = blockIdx.x;
    const int xcd   = b & 7;
    const int slot  = b >> 3;                // 0..127
    // decorrelated map: neighbors differ in r (uncorrelated cnt);
    // XCD x owns t-tiles {2x, 2x+1} -> 2 MB x-slice stays L2-resident
    const int ttile = xcd * 2 + (slot >> 6);
    const int t0    = ttile * BT;
    const int r     = slot & 63;

    const int cnt = counts[r];
    const unsigned int* lst = lists + r * LSTRIDE;

    const int tid  = threadIdx.x;
    const int wave = tid >> 6;
    const int lane = tid & 63;
    const int lrow = lane & 15;
    const int lk16 = lane >> 4;

    f32x4 acc[8] = {};

    const int srr    = lane >> 3;
    const int scol16 = lane & 7;

    auto stageA = [&](int i, int buf) {
        const int c = (int)(lst[i] >> 16);
        const unsigned short* src = xb2 + ((size_t)c * T_DIM + t0) * 64;
#pragma unroll
        for (int ch = 0; ch < 4; ++ch) {
            const int rbase = wave * 32 + ch * 8;
            const int row   = rbase + srr;
            const int sc    = (scol16 ^ (row & 7)) * 8;   // inverse-swizzled source
            gld16(src + (size_t)row * 64 + sc, &sA[buf][rbase * 128]);
        }
    };

    auto loadB = [&](int i, bf16x8& b0, bf16x8& b1) {
        const int n = (int)(lst[i] & 0xFFFF);
        const unsigned short* vp =
            vb + (size_t)n * 4096 + (wave * 16 + lrow) * 64 + lk16 * 8;
        b0 = *(const bf16x8*)(vp);
        b1 = *(const bf16x8*)(vp + 32);
    };

    auto compute = [&](int buf, bf16x8 b0, bf16x8 b1) {
#pragma unroll
        for (int ks = 0; ks < 2; ++ks) {
            bf16x8 afr[8];
#pragma unroll
            for (int tf = 0; tf < 8; ++tf) {
                const int trow = tf * 16 + lrow;
                int abyte = trow * 128 + (ks * 32 + lk16 * 8) * 2;
                abyte ^= (trow & 7) << 4;
                afr[tf] = *(const bf16x8*)(&sA[buf][abyte]);
            }
            const bf16x8 bb = ks ? b1 : b0;
#pragma unroll
            for (int tf = 0; tf < 8; ++tf)
                acc[tf] = __builtin_amdgcn_mfma_f32_16x16x32_bf16(
                    afr[tf], bb, acc[tf], 0, 0, 0);
        }
    };

    // exact outstanding-op wait: each staged-not-consumed iter = 4 gld16 + 2 B
    auto waitfor = [&](int j) {
        const int rem = cnt - 1 - j;
        if (rem >= 2)      asm volatile("s_waitcnt vmcnt(12)" ::: "memory");
        else if (rem == 1) asm volatile("s_waitcnt vmcnt(6)"  ::: "memory");
        else               asm volatile("s_waitcnt vmcnt(0)"  ::: "memory");
    };

    bf16x8 a0, a1, bb0, bb1, c0, c1;   // 2-deep B prefetch, static names
    if (cnt > 0) { stageA(0, 0); loadB(0, a0, a1); }
    if (cnt > 1) { stageA(1, 1); loadB(1, bb0, bb1); }
    for (int i = 0; i < cnt; i += 3) {
        if (i + 2 < cnt) { stageA(i + 2, 2); loadB(i + 2, c0, c1); }
        waitfor(i);
        __builtin_amdgcn_s_barrier();
        compute(0, a0, a1);
        __builtin_amdgcn_s_barrier();
        if (i + 1 >= cnt) break;

        if (i + 3 < cnt) { stageA(i + 3, 0); loadB(i + 3, a0, a1); }
        waitfor(i + 1);
        __builtin_amdgcn_s_barrier();
        compute(1, bb0, bb1);
        __builtin_amdgcn_s_barrier();
        if (i + 2 >= cnt) break;

        if (i + 4 < cnt) { stageA(i + 4, 1); loadB(i + 4, bb0, bb1); }
        waitfor(i + 2);
        __builtin_amdgcn_s_barrier();
        compute(2, c0, c1);
        __builtin_amdgcn_s_barrier();
    }

    // Epilogue: C/D layout col(lane&15)=m, row((lane>>4)*4+reg)=t
    const int mg = r * 64 + wave * 16 + (lane & 15);
    const float bv = bias[mg];
    const int tbase = t0 + (lane >> 4) * 4;
#pragma unroll
    for (int tf = 0; tf < 8; ++tf) {
#pragma unroll
        for (int reg = 0; reg < 4; ++reg) {
            const int t = tbase + tf * 16 + reg;
            float v = acc[tf][reg] + bv;
            float inner = 0.7978845608f * (v + 0.044715f * v * v * v);
            inner = fminf(fmaxf(inner, -15.0f), 15.0f);
            const float e  = __expf(2.0f * inner);
            const float th = 1.0f - 2.0f / (e + 1.0f);
            out[(size_t)t * M_DIM + mg] = v * 0.5f * (1.0f + th);
        }
    }
}

// ---- fallback (fp32, self-contained) if ws is too small ----
__global__ __launch_bounds__(256, 2) void fsl_mfma_fallback(
    const float* __restrict__ x, const float* __restrict__ values,
    const float* __restrict__ bias, const int* __restrict__ brows,
    const int* __restrict__ bcols, float* __restrict__ out)
{
    __shared__ __align__(16) unsigned char sA[2][64 * 128];
    __shared__ __align__(16) unsigned char sB[2][64 * 128];
    __shared__ int s_list[NB];
    __shared__ int s_cnt;

    const int tid = threadIdx.x;
    const int r   = blockIdx.x >> 5;
    const int t0  = (blockIdx.x & 31) * 64;

    if (tid == 0) s_cnt = 0;
    __syncthreads();
    for (int n = tid; n < NB; n += 256) {
        if (brows[n] == r) {
            int p = atomicAdd(&s_cnt, 1);
            s_list[p] = n;
        }
    }
    __syncthreads();
    const int cnt = s_cnt;

    const int wave = tid >> 6;
    const int lane = tid & 63;
    const int wt   = wave >> 1;
    const int wm   = wave & 1;
    const int lrow = lane & 15;
    const int lk8  = (lane >> 4) * 8;
    const int srow = tid >> 4;
    const int scol = tid & 15;

    f32x4 acc[2][2] = {};
    float4 ra[4], rb[4];

    auto stage_load = [&](int i) {
        const int n = s_list[i];
        const int c = bcols[n];
        const float* xp = x + (size_t)(t0 + srow) * K_DIM + c * 64 + scol * 4;
        const float* vp = values + (size_t)n * 4096 + srow * 64 + scol * 4;
#pragma unroll
        for (int j = 0; j < 4; ++j) {
            ra[j] = *(const float4*)(xp + (size_t)(j * 16) * K_DIM);
            rb[j] = *(const float4*)(vp + j * 16 * 64);
        }
    };
    auto stage_write = [&](int buf) {
#pragma unroll
        for (int j = 0; j < 4; ++j) {
            const int row = srow + j * 16;
            int byte = row * 128 + scol * 8;
            byte ^= (row & 7) << 4;
            uint2 pa, pb;
            pa.x = (unsigned)f2bf(ra[j].x) | ((unsigned)f2bf(ra[j].y) << 16);
            pa.y = (unsigned)f2bf(ra[j].z) | ((unsigned)f2bf(ra[j].w) << 16);
            pb.x = (unsigned)f2bf(rb[j].x) | ((unsigned)f2bf(rb[j].y) << 16);
            pb.y = (unsigned)f2bf(rb[j].z) | ((unsigned)f2bf(rb[j].w) << 16);
            *(uint2*)(&sA[buf][byte]) = pa;
            *(uint2*)(&sB[buf][byte]) = pb;
        }
    };
    auto compute = [&](int buf) {
#pragma unroll
        for (int ks = 0; ks < 2; ++ks) {
            bf16x8 a[2], bb[2];
#pragma unroll
            for (int f = 0; f < 2; ++f) {
                const int trow = wt * 32 + f * 16 + lrow;
                int abyte = trow * 128 + (ks * 32 + lk8) * 2;
                abyte ^= (trow & 7) << 4;
                a[f] = *(const bf16x8*)(&sA[buf][abyte]);
                const int mrow = wm * 32 + f * 16 + lrow;
                int bbyte = mrow * 128 + (ks * 32 + lk8) * 2;
                bbyte ^= (mrow & 7) << 4;
                bb[f] = *(const bf16x8*)(&sB[buf][bbyte]);
            }
#pragma unroll
            for (int ft = 0; ft < 2; ++ft)
#pragma unroll
                for (int fm = 0; fm < 2; ++fm)
                    acc[ft][fm] = __builtin_amdgcn_mfma_f32_16x16x32_bf16(
                        a[ft], bb[fm], acc[ft][fm], 0, 0, 0);
        }
    };

    if (cnt > 0) { stage_load(0); stage_write(0); }
    for (int i = 0; i < cnt; ++i) {
        __syncthreads();
        const bool more = (i + 1 < cnt);
        if (more) stage_load(i + 1);
        compute(i & 1);
        if (more) stage_write((i + 1) & 1);
    }

    const int mcol  = lane & 15;
    const int trow4 = (lane >> 4) * 4;
#pragma unroll
    for (int ft = 0; ft < 2; ++ft) {
#pragma unroll
        for (int fm = 0; fm < 2; ++fm) {
            const int mg = r * 64 + wm * 32 + fm * 16 + mcol;
            const float bv = bias[mg];
#pragma unroll
            for (int reg = 0; reg < 4; ++reg) {
                const int t = t0 + wt * 32 + ft * 16 + trow4 + reg;
                float v = acc[ft][fm][reg] + bv;
                float inner = 0.7978845608f * (v + 0.044715f * v * v * v);
                inner = fminf(fmaxf(inner, -15.0f), 15.0f);
                const float e  = __expf(2.0f * inner);
                const float th = 1.0f - 2.0f / (e + 1.0f);
                out[(size_t)t * M_DIM + mg] = v * 0.5f * (1.0f + th);
            }
        }
    }
}

extern "C" void kernel_launch(void* const* d_in, const int* in_sizes, int n_in,
                              void* d_out, int out_size, void* d_ws, size_t ws_size,
                              hipStream_t stream) {
    const float* x      = (const float*)d_in[0];
    const float* values = (const float*)d_in[1];
    const float* bias   = (const float*)d_in[2];
    const int*   brows  = (const int*)d_in[3];
    const int*   bcols  = (const int*)d_in[4];
    float* out = (float*)d_out;

    const size_t x_elems = (size_t)T_DIM * K_DIM;        // 8,388,608
    const size_t v_elems = (size_t)NB * 64 * 64;         // 4,194,304
    const size_t sched_b = 64 * 4 + 64 * LSTRIDE * 4;    // counts + lists
    const size_t ws_need = (x_elems + v_elems) * 2 + sched_b;

    if (ws_size >= ws_need) {
        unsigned short* xb2   = (unsigned short*)d_ws;
        unsigned short* vb    = xb2 + x_elems;
        int*            cnts  = (int*)(vb + v_elems);
        unsigned int*   lists = (unsigned int*)(cnts + 64);
        prep_kernel<<<NPREP + 1, 256, 0, stream>>>(x, values, xb2, vb,
                                                   brows, bcols, cnts, lists);
        fsl_main<<<dim3(1024), 256, 0, stream>>>(xb2, vb, bias, cnts, lists, out);
    } else {
        fsl_mfma_fallback<<<dim3(64 * 32), 256, 0, stream>>>(
            x, values, bias, brows, bcols, out);
    }
}